// Round 5
// baseline (193.652 us; speedup 1.0000x reference)
//
#include <hip/hip_runtime.h>
#include <hip/hip_bf16.h>
#include <math.h>

#define BB 32
#define NN 512
#define MM 64
#define DD 128
#define TILE 64
#define NTILES 8

typedef __attribute__((ext_vector_type(8))) short s8v;      // 8 bf16 MFMA A/B frag
typedef __attribute__((ext_vector_type(4))) float f4v;      // MFMA C/D frag
typedef __attribute__((ext_vector_type(4))) unsigned short u4v;
typedef __attribute__((ext_vector_type(8))) unsigned short u8v;

#define MFMA(a, b, c) __builtin_amdgcn_mfma_f32_16x16x32_bf16((a), (b), (c), 0, 0, 0)

__device__ inline unsigned short f2b(float f) {
  union { __hip_bfloat16 b; unsigned short u; } cv;
  cv.b = __float2bfloat16(f);
  return cv.u;
}

// row-swizzles: elem ^= (row&7)<<3 (proven in r3/r4)
__device__ inline int idxV(int r, int k)  { return r * 128 + (k ^ ((r & 7) << 3)); }
__device__ inline int idx64(int r, int k) { return r * 64  + (k ^ ((r & 7) << 3)); }

struct __align__(16) SMem {
  unsigned short VA[64 * 128];                                  // V bf16 (dot A)
  union { unsigned short Sb[64 * 128]; unsigned short VT[128 * 64]; };  // S (pre-loop) / V^T (loop)
  union { unsigned short Gb[64 * 64];  unsigned short Eb[64 * 64]; };   // Gram (pre-loop) / E (loop)
  unsigned short ET[64 * 64];                                   // E^T (bt A)
  float red_sv[2][16][16][4];   // sv-numerator partials [hf][rowgrp][l15][q]
  float red_qp[2][16][16][4];   // quad-form partials; reused for ||bt||^2
  float red_s[8][64];           // ss col-sum partials [wave][col]
  float nv_l[2][64];            // double-buffered (finisher reads prev tile's)
  float rnv_l[64];
  float ns_l[64], rns_l[64];
  float ssnum[64];
};

extern "C" __global__ void __launch_bounds__(512, 4)
mv_mfma3(const float* __restrict__ Vg, const float* __restrict__ Sg,
         float* __restrict__ out)
{
  extern __shared__ char smraw[];
  SMem& sm = *reinterpret_cast<SMem*>(smraw);

  const int t    = threadIdx.x;
  const int lane = t & 63;
  const int w    = t >> 6;
  const int l15  = lane & 15;
  const int g    = lane >> 4;          // 0..3
  const int bi   = blockIdx.x >> 5;
  const int bj   = blockIdx.x & 31;

  const float* Vi = Vg + (size_t)bi * NN * DD;
  const float* Sj = Sg + (size_t)bj * MM * DD;

  const int nb  = w >> 1;              // 16-row block
  const int hf  = w & 1;               // column half
  const int cB0 = hf * 32 + l15;
  const int cB1 = cB0 + 16;

  const int r = t >> 3;                // staging row 0..63
  const int c = t & 7;                 // staging 16-col chunk

  // ---- stage S (bf16, row-chunk mapping) + ns/rns ----
  {
    const float* Sp = Sj + r * DD + c * 16;
    float4 f0 = reinterpret_cast<const float4*>(Sp)[0];
    float4 f1 = reinterpret_cast<const float4*>(Sp)[1];
    float4 f2 = reinterpret_cast<const float4*>(Sp)[2];
    float4 f3 = reinterpret_cast<const float4*>(Sp)[3];
    u8v lo = { f2b(f0.x), f2b(f0.y), f2b(f0.z), f2b(f0.w),
               f2b(f1.x), f2b(f1.y), f2b(f1.z), f2b(f1.w) };
    u8v hi = { f2b(f2.x), f2b(f2.y), f2b(f2.z), f2b(f2.w),
               f2b(f3.x), f2b(f3.y), f2b(f3.z), f2b(f3.w) };
    *reinterpret_cast<u8v*>(&sm.Sb[idxV(r, c * 16)])     = lo;
    *reinterpret_cast<u8v*>(&sm.Sb[idxV(r, c * 16 + 8)]) = hi;
    float s = f0.x*f0.x + f0.y*f0.y + f0.z*f0.z + f0.w*f0.w
            + f1.x*f1.x + f1.y*f1.y + f1.z*f1.z + f1.w*f1.w
            + f2.x*f2.x + f2.y*f2.y + f2.z*f2.z + f2.w*f2.w
            + f3.x*f3.x + f3.y*f3.y + f3.z*f3.z + f3.w*f3.w;
    s += __shfl_xor(s, 1, 64);
    s += __shfl_xor(s, 2, 64);
    s += __shfl_xor(s, 4, 64);
    if (c == 0) {
      const float rs = rsqrtf(s);
      sm.ns_l[r] = s * rs;
      sm.rns_l[r] = rs;
    }
  }
  if (t < 64) sm.ssnum[t] = 0.f;
  __syncthreads();

  // ---- Gram(S) via MFMA ----
  {
    f4v g0 = {0.f,0.f,0.f,0.f}, g1 = {0.f,0.f,0.f,0.f};
    #pragma unroll
    for (int ks = 0; ks < 4; ++ks) {
      s8v a  = *reinterpret_cast<const s8v*>(&sm.Sb[idxV(nb * 16 + l15, ks * 32 + g * 8)]);
      s8v b0 = *reinterpret_cast<const s8v*>(&sm.Sb[idxV(cB0,          ks * 32 + g * 8)]);
      s8v b1 = *reinterpret_cast<const s8v*>(&sm.Sb[idxV(cB1,          ks * 32 + g * 8)]);
      g0 = MFMA(a, b0, g0);
      g1 = MFMA(a, b1, g1);
    }
    #pragma unroll
    for (int q = 0; q < 4; ++q) {
      const int row = nb * 16 + g * 4 + q;
      sm.Gb[idx64(row, cB0)] = f2b(g0[q]);
      sm.Gb[idx64(row, cB1)] = f2b(g1[q]);
    }
  }
  __syncthreads();

  // ---- hoist loop-invariant fragments into registers ----
  s8v sfr0[4], sfr1[4], gfr0[2], gfr1[2];
  #pragma unroll
  for (int ks = 0; ks < 4; ++ks) {
    sfr0[ks] = *reinterpret_cast<const s8v*>(&sm.Sb[idxV(cB0, ks * 32 + g * 8)]);
    sfr1[ks] = *reinterpret_cast<const s8v*>(&sm.Sb[idxV(cB1, ks * 32 + g * 8)]);
  }
  #pragma unroll
  for (int ks = 0; ks < 2; ++ks) {
    gfr0[ks] = *reinterpret_cast<const s8v*>(&sm.Gb[idx64(cB0, ks * 32 + g * 8)]);
    gfr1[ks] = *reinterpret_cast<const s8v*>(&sm.Gb[idx64(cB1, ks * 32 + g * 8)]);
  }
  const float rns0r = sm.rns_l[cB0];
  const float rns1r = sm.rns_l[cB1];

  f4v bt4[4] = {{0.f,0.f,0.f,0.f},{0.f,0.f,0.f,0.f},{0.f,0.f,0.f,0.f},{0.f,0.f,0.f,0.f}};
  float svacc = 0.f;

  for (int tt = 0; tt < NTILES; ++tt) {
    __syncthreads();                   // B1: Sb/Gb hoisted (tt=0) / VT,ET,red readers done

    // ---- stage V: VA (row-major) + VT (transposed) from the same registers ----
    {
      const float* Vr = Vi + (size_t)tt * TILE * DD + r * DD + c * 16;
      float4 f0 = reinterpret_cast<const float4*>(Vr)[0];
      float4 f1 = reinterpret_cast<const float4*>(Vr)[1];
      float4 f2 = reinterpret_cast<const float4*>(Vr)[2];
      float4 f3 = reinterpret_cast<const float4*>(Vr)[3];
      unsigned short vb16[16] = {
        f2b(f0.x), f2b(f0.y), f2b(f0.z), f2b(f0.w),
        f2b(f1.x), f2b(f1.y), f2b(f1.z), f2b(f1.w),
        f2b(f2.x), f2b(f2.y), f2b(f2.z), f2b(f2.w),
        f2b(f3.x), f2b(f3.y), f2b(f3.z), f2b(f3.w) };
      u8v lo = { vb16[0], vb16[1], vb16[2], vb16[3], vb16[4], vb16[5], vb16[6], vb16[7] };
      u8v hi = { vb16[8], vb16[9], vb16[10], vb16[11], vb16[12], vb16[13], vb16[14], vb16[15] };
      *reinterpret_cast<u8v*>(&sm.VA[idxV(r, c * 16)])     = lo;
      *reinterpret_cast<u8v*>(&sm.VA[idxV(r, c * 16 + 8)]) = hi;
      // V^T scatter: VT[d][n], swizzle f(d) = ((d&7)^(d>>4))&7 — write-conflict-free
      #pragma unroll
      for (int q = 0; q < 8; ++q) {
        const int adr = ((c * 16 + q) << 6) + (r ^ (((q ^ c) & 7) << 3));
        sm.VT[adr]       = vb16[q];
        sm.VT[adr + 512] = vb16[q + 8];   // d+8: same swizzle term, +8*64 elems
      }
      float s = f0.x*f0.x + f0.y*f0.y + f0.z*f0.z + f0.w*f0.w
              + f1.x*f1.x + f1.y*f1.y + f1.z*f1.z + f1.w*f1.w
              + f2.x*f2.x + f2.y*f2.y + f2.z*f2.z + f2.w*f2.w
              + f3.x*f3.x + f3.y*f3.y + f3.z*f3.z + f3.w*f3.w;
      s += __shfl_xor(s, 1, 64);
      s += __shfl_xor(s, 2, 64);
      s += __shfl_xor(s, 4, 64);
      if (c == 0) {
        const float rs = rsqrtf(s);
        sm.nv_l[tt & 1][r] = s * rs;
        sm.rnv_l[r] = rs;
      }
    }
    // ---- pipelined finisher for PREVIOUS tile (overlaps staging VMEM) ----
    if (tt > 0 && t < 64) {
      const int rg = t >> 2, qq = t & 3;
      float sv_n = 0.f, qf = 0.f;
      #pragma unroll
      for (int l = 0; l < 16; ++l) {
        sv_n += sm.red_sv[0][rg][l][qq] + sm.red_sv[1][rg][l][qq];
        qf   += sm.red_qp[0][rg][l][qq] + sm.red_qp[1][rg][l][qq];
      }
      svacc += sv_n / (sm.nv_l[(tt & 1) ^ 1][t] * sqrtf(qf));
      const int hh = t >> 5;
      float ssn = 0.f;
      #pragma unroll
      for (int n2 = 0; n2 < 4; ++n2) ssn += sm.red_s[n2 * 2 + hh][t];
      sm.ssnum[t] += ssn;
    }
    __syncthreads();                   // B2

    // ---- dot MFMA (B-frags from registers) + glue, all in registers ----
    f4v a0 = {0.f,0.f,0.f,0.f}, a1 = {0.f,0.f,0.f,0.f};
    {
      const int ar = nb * 16 + l15;
      #pragma unroll
      for (int ks = 0; ks < 4; ++ks) {
        s8v av = *reinterpret_cast<const s8v*>(&sm.VA[idxV(ar, ks * 32 + g * 8)]);
        a0 = MFMA(av, sfr0[ks], a0);
        a1 = MFMA(av, sfr1[ks], a1);
      }
    }
    float e0[4], e1[4];
    {
      const float4 rv = *reinterpret_cast<const float4*>(&sm.rnv_l[nb * 16 + g * 4]);
      float sv4[4];
      float ss0 = 0.f, ss1 = 0.f;
      unsigned short eb0[4], eb1[4];
      #pragma unroll
      for (int q = 0; q < 4; ++q) {
        const float rvq = (q == 0) ? rv.x : (q == 1) ? rv.y : (q == 2) ? rv.z : rv.w;
        const float c0 = a0[q] * (rvq * rns0r);      // cosine (EPS drop: 1e-16 rel)
        const float c1 = a1[q] * (rvq * rns1r);
        const float e0q = __expf(c0);                // c in [-1,1]: no max-shift needed
        const float e1q = __expf(c1);
        const float w0 = e0q * a0[q], w1 = e1q * a1[q];  // e * rawdot
        sv4[q] = w0 + w1;
        ss0 += w0; ss1 += w1;
        eb0[q] = f2b(e0q); eb1[q] = f2b(e1q);
        const int row = nb * 16 + g * 4 + q;
        sm.Eb[idx64(row, cB0)] = eb0[q];
        sm.Eb[idx64(row, cB1)] = eb1[q];
        e0[q] = e0q; e1[q] = e1q;
      }
      u4v et0 = { eb0[0], eb0[1], eb0[2], eb0[3] };
      u4v et1 = { eb1[0], eb1[1], eb1[2], eb1[3] };
      *reinterpret_cast<u4v*>(&sm.ET[idx64(cB0, nb * 16 + g * 4)]) = et0;
      *reinterpret_cast<u4v*>(&sm.ET[idx64(cB1, nb * 16 + g * 4)]) = et1;
      *reinterpret_cast<float4*>(&sm.red_sv[hf][nb * 4 + g][l15][0]) =
          make_float4(sv4[0], sv4[1], sv4[2], sv4[3]);
      ss0 += __shfl_xor(ss0, 16, 64);  ss0 += __shfl_xor(ss0, 32, 64);
      ss1 += __shfl_xor(ss1, 16, 64);  ss1 += __shfl_xor(ss1, 32, 64);
      if (g == 0) { sm.red_s[w][cB0] = ss0; sm.red_s[w][cB1] = ss1; }
    }
    __syncthreads();                   // B3

    // ---- quad form (E.G, B-frags from registers) ----
    {
      f4v fa0 = {0.f,0.f,0.f,0.f}, fa1 = {0.f,0.f,0.f,0.f};
      #pragma unroll
      for (int ks = 0; ks < 2; ++ks) {
        s8v ea = *reinterpret_cast<const s8v*>(&sm.Eb[idx64(nb * 16 + l15, ks * 32 + g * 8)]);
        fa0 = MFMA(ea, gfr0[ks], fa0);
        fa1 = MFMA(ea, gfr1[ks], fa1);
      }
      *reinterpret_cast<float4*>(&sm.red_qp[hf][nb * 4 + g][l15][0]) =
          make_float4(e0[0]*fa0[0] + e1[0]*fa1[0], e0[1]*fa0[1] + e1[1]*fa1[1],
                      e0[2]*fa0[2] + e1[2]*fa1[2], e0[3]*fa0[3] + e1[3]*fa1[3]);
    }
    // ---- bt += E^T.V via MFMA (B from VT) ----
    {
      const int xr = l15 & 7;
      #pragma unroll
      for (int ks = 0; ks < 2; ++ks) {
        s8v pa = *reinterpret_cast<const s8v*>(&sm.ET[idx64(nb * 16 + l15, ks * 32 + g * 8)]);
        const int k0 = ks * 32 + g * 8;
        #pragma unroll
        for (int dt = 0; dt < 4; ++dt) {
          const int rowv = (hf * 4 + dt) * 16 + l15;
          const int elem = (rowv << 6) + (k0 ^ (((xr ^ (hf * 4 + dt)) & 7) << 3));
          s8v vb = *reinterpret_cast<const s8v*>(&sm.VT[elem]);
          bt4[dt] = MFMA(pa, vb, bt4[dt]);
        }
      }
    }
  }

  // ---- epilogue ----
  __syncthreads();
  if (t < 64) {                        // finisher for tile 7
    const int rg = t >> 2, qq = t & 3;
    float sv_n = 0.f, qf = 0.f;
    #pragma unroll
    for (int l = 0; l < 16; ++l) {
      sv_n += sm.red_sv[0][rg][l][qq] + sm.red_sv[1][rg][l][qq];
      qf   += sm.red_qp[0][rg][l][qq] + sm.red_qp[1][rg][l][qq];
    }
    svacc += sv_n / (sm.nv_l[1][t] * sqrtf(qf));
    const int hh = t >> 5;
    float ssn = 0.f;
    #pragma unroll
    for (int n2 = 0; n2 < 4; ++n2) ssn += sm.red_s[n2 * 2 + hh][t];
    sm.ssnum[t] += ssn;
  }
  __syncthreads();
  {
    float bq[4];
    #pragma unroll
    for (int q = 0; q < 4; ++q)
      bq[q] = bt4[0][q]*bt4[0][q] + bt4[1][q]*bt4[1][q]
            + bt4[2][q]*bt4[2][q] + bt4[3][q]*bt4[3][q];
    *reinterpret_cast<float4*>(&sm.red_qp[hf][nb * 4 + g][l15][0]) =
        make_float4(bq[0], bq[1], bq[2], bq[3]);
  }
  __syncthreads();
  if (t < 64) {
    const int rg = t >> 2, qq = t & 3;
    float btq = 0.f;
    #pragma unroll
    for (int l = 0; l < 16; ++l)
      btq += sm.red_qp[0][rg][l][qq] + sm.red_qp[1][rg][l][qq];
    float ssv = sm.ssnum[t] / (sm.ns_l[t] * sqrtf(btq));
    float svv = svacc;
    #pragma unroll
    for (int msk = 32; msk >= 1; msk >>= 1) {
      ssv += __shfl_xor(ssv, msk, 64);
      svv += __shfl_xor(svv, msk, 64);
    }
    if (t == 0) {
      out[bi * BB + bj]           = svv * (1.0f / NN);
      out[BB * BB + bj * BB + bi] = ssv * (1.0f / MM);  // transposed output
    }
  }
}

extern "C" void kernel_launch(void* const* d_in, const int* in_sizes, int n_in,
                              void* d_out, int out_size, void* d_ws, size_t ws_size,
                              hipStream_t stream) {
  const float* V = (const float*)d_in[0];   // [32, 512, 128] f32
  const float* S = (const float*)d_in[1];   // [32, 64, 128] f32
  float* out = (float*)d_out;               // [2048] f32

  static_assert(sizeof(SMem) <= 80 * 1024, "need 2 blocks/CU");
  hipFuncSetAttribute(reinterpret_cast<const void*>(mv_mfma3),
                      hipFuncAttributeMaxDynamicSharedMemorySize,
                      (int)sizeof(SMem));
  mv_mfma3<<<dim3(BB * BB), dim3(512), sizeof(SMem), stream>>>(V, S, out);
}

// Round 6
// 145.859 us; speedup vs baseline: 1.3277x; 1.3277x over previous
//
#include <hip/hip_runtime.h>
#include <hip/hip_bf16.h>
#include <math.h>

#define BB 32
#define NN 512
#define MM 64
#define DD 128
#define TILE 64
#define NTILES 8

typedef __attribute__((ext_vector_type(8))) short s8v;      // 8 bf16 MFMA A/B frag
typedef __attribute__((ext_vector_type(4))) float f4v;      // MFMA C/D frag
typedef __attribute__((ext_vector_type(4))) unsigned short u4v;
typedef __attribute__((ext_vector_type(8))) unsigned short u8v;

#define MFMA(a, b, c) __builtin_amdgcn_mfma_f32_16x16x32_bf16((a), (b), (c), 0, 0, 0)

__device__ inline unsigned short f2b(float f) {
  union { __hip_bfloat16 b; unsigned short u; } cv;
  cv.b = __float2bfloat16(f);
  return cv.u;
}

// row-swizzles: elem ^= (row&7)<<3 (proven in r3/r4)
__device__ inline int idxV(int r, int k)  { return r * 128 + (k ^ ((r & 7) << 3)); }
__device__ inline int idx64(int r, int k) { return r * 64  + (k ^ ((r & 7) << 3)); }

struct __align__(16) SMem {
  unsigned short VA[64 * 128];                                  // V bf16 (dot A)
  union { unsigned short Sb[64 * 128]; unsigned short VT[128 * 64]; };  // S (pre-loop) / V^T (loop)
  union { unsigned short Gb[64 * 64];  unsigned short Eb[64 * 64]; };   // Gram (pre-loop) / E (loop)
  unsigned short ET[64 * 64];                                   // E^T (bt A)
  float red_sv[2][16][16][4];   // sv-numerator partials [hf][rowgrp][l15][q]
  float red_qp[2][16][16][4];   // quad-form partials; reused for ||bt||^2
  float red_s[8][64];           // ss col-sum partials [wave][col]
  float nv_l[2][64];            // double-buffered (finisher reads prev tile's)
  float rnv_l[64];
  float ns_l[64], rns_l[64];
  float ssnum[64];
};

// NOTE: __launch_bounds__ 2nd arg behaves as min BLOCKS/CU (CUDA semantics):
// (512,4) capped VGPR at 64 -> r5's hoisted fragments spilled (82 MB scratch
// writes/dispatch). (512,2) -> 16 waves/CU -> 128-VGPR cap; LDS (67.5 KB)
// already limits us to 2 blocks/CU, so occupancy is unchanged.
extern "C" __global__ void __launch_bounds__(512, 2)
mv_mfma3(const float* __restrict__ Vg, const float* __restrict__ Sg,
         float* __restrict__ out)
{
  extern __shared__ char smraw[];
  SMem& sm = *reinterpret_cast<SMem*>(smraw);

  const int t    = threadIdx.x;
  const int lane = t & 63;
  const int w    = t >> 6;
  const int l15  = lane & 15;
  const int g    = lane >> 4;          // 0..3
  const int bi   = blockIdx.x >> 5;
  const int bj   = blockIdx.x & 31;

  const float* Vi = Vg + (size_t)bi * NN * DD;
  const float* Sj = Sg + (size_t)bj * MM * DD;

  const int nb  = w >> 1;              // 16-row block
  const int hf  = w & 1;               // column half
  const int cB0 = hf * 32 + l15;
  const int cB1 = cB0 + 16;

  const int r = t >> 3;                // staging row 0..63
  const int c = t & 7;                 // staging 16-col chunk

  // ---- stage S (bf16, row-chunk mapping) + ns/rns ----
  {
    const float* Sp = Sj + r * DD + c * 16;
    float4 f0 = reinterpret_cast<const float4*>(Sp)[0];
    float4 f1 = reinterpret_cast<const float4*>(Sp)[1];
    float4 f2 = reinterpret_cast<const float4*>(Sp)[2];
    float4 f3 = reinterpret_cast<const float4*>(Sp)[3];
    u8v lo = { f2b(f0.x), f2b(f0.y), f2b(f0.z), f2b(f0.w),
               f2b(f1.x), f2b(f1.y), f2b(f1.z), f2b(f1.w) };
    u8v hi = { f2b(f2.x), f2b(f2.y), f2b(f2.z), f2b(f2.w),
               f2b(f3.x), f2b(f3.y), f2b(f3.z), f2b(f3.w) };
    *reinterpret_cast<u8v*>(&sm.Sb[idxV(r, c * 16)])     = lo;
    *reinterpret_cast<u8v*>(&sm.Sb[idxV(r, c * 16 + 8)]) = hi;
    float s = f0.x*f0.x + f0.y*f0.y + f0.z*f0.z + f0.w*f0.w
            + f1.x*f1.x + f1.y*f1.y + f1.z*f1.z + f1.w*f1.w
            + f2.x*f2.x + f2.y*f2.y + f2.z*f2.z + f2.w*f2.w
            + f3.x*f3.x + f3.y*f3.y + f3.z*f3.z + f3.w*f3.w;
    s += __shfl_xor(s, 1, 64);
    s += __shfl_xor(s, 2, 64);
    s += __shfl_xor(s, 4, 64);
    if (c == 0) {
      const float rs = rsqrtf(s);
      sm.ns_l[r] = s * rs;
      sm.rns_l[r] = rs;
    }
  }
  if (t < 64) sm.ssnum[t] = 0.f;
  __syncthreads();

  // ---- Gram(S) via MFMA ----
  {
    f4v g0 = {0.f,0.f,0.f,0.f}, g1 = {0.f,0.f,0.f,0.f};
    #pragma unroll
    for (int ks = 0; ks < 4; ++ks) {
      s8v a  = *reinterpret_cast<const s8v*>(&sm.Sb[idxV(nb * 16 + l15, ks * 32 + g * 8)]);
      s8v b0 = *reinterpret_cast<const s8v*>(&sm.Sb[idxV(cB0,          ks * 32 + g * 8)]);
      s8v b1 = *reinterpret_cast<const s8v*>(&sm.Sb[idxV(cB1,          ks * 32 + g * 8)]);
      g0 = MFMA(a, b0, g0);
      g1 = MFMA(a, b1, g1);
    }
    #pragma unroll
    for (int q = 0; q < 4; ++q) {
      const int row = nb * 16 + g * 4 + q;
      sm.Gb[idx64(row, cB0)] = f2b(g0[q]);
      sm.Gb[idx64(row, cB1)] = f2b(g1[q]);
    }
  }
  __syncthreads();

  // ---- hoist loop-invariant fragments into registers ----
  s8v sfr0[4], sfr1[4], gfr0[2], gfr1[2];
  #pragma unroll
  for (int ks = 0; ks < 4; ++ks) {
    sfr0[ks] = *reinterpret_cast<const s8v*>(&sm.Sb[idxV(cB0, ks * 32 + g * 8)]);
    sfr1[ks] = *reinterpret_cast<const s8v*>(&sm.Sb[idxV(cB1, ks * 32 + g * 8)]);
  }
  #pragma unroll
  for (int ks = 0; ks < 2; ++ks) {
    gfr0[ks] = *reinterpret_cast<const s8v*>(&sm.Gb[idx64(cB0, ks * 32 + g * 8)]);
    gfr1[ks] = *reinterpret_cast<const s8v*>(&sm.Gb[idx64(cB1, ks * 32 + g * 8)]);
  }
  const float rns0r = sm.rns_l[cB0];
  const float rns1r = sm.rns_l[cB1];

  f4v bt4[4] = {{0.f,0.f,0.f,0.f},{0.f,0.f,0.f,0.f},{0.f,0.f,0.f,0.f},{0.f,0.f,0.f,0.f}};
  float svacc = 0.f;

  for (int tt = 0; tt < NTILES; ++tt) {
    __syncthreads();                   // B1: Sb/Gb hoisted (tt=0) / VT,ET,red readers done

    // ---- stage V: VA (row-major) + VT (transposed) from the same registers ----
    {
      const float* Vr = Vi + (size_t)tt * TILE * DD + r * DD + c * 16;
      float4 f0 = reinterpret_cast<const float4*>(Vr)[0];
      float4 f1 = reinterpret_cast<const float4*>(Vr)[1];
      float4 f2 = reinterpret_cast<const float4*>(Vr)[2];
      float4 f3 = reinterpret_cast<const float4*>(Vr)[3];
      unsigned short vb16[16] = {
        f2b(f0.x), f2b(f0.y), f2b(f0.z), f2b(f0.w),
        f2b(f1.x), f2b(f1.y), f2b(f1.z), f2b(f1.w),
        f2b(f2.x), f2b(f2.y), f2b(f2.z), f2b(f2.w),
        f2b(f3.x), f2b(f3.y), f2b(f3.z), f2b(f3.w) };
      u8v lo = { vb16[0], vb16[1], vb16[2], vb16[3], vb16[4], vb16[5], vb16[6], vb16[7] };
      u8v hi = { vb16[8], vb16[9], vb16[10], vb16[11], vb16[12], vb16[13], vb16[14], vb16[15] };
      *reinterpret_cast<u8v*>(&sm.VA[idxV(r, c * 16)])     = lo;
      *reinterpret_cast<u8v*>(&sm.VA[idxV(r, c * 16 + 8)]) = hi;
      // V^T scatter: VT[d][n], swizzle f(d) = ((d&7)^(d>>4))&7 — write-conflict-free
      #pragma unroll
      for (int q = 0; q < 8; ++q) {
        const int adr = ((c * 16 + q) << 6) + (r ^ (((q ^ c) & 7) << 3));
        sm.VT[adr]       = vb16[q];
        sm.VT[adr + 512] = vb16[q + 8];   // d+8: same swizzle term, +8*64 elems
      }
      float s = f0.x*f0.x + f0.y*f0.y + f0.z*f0.z + f0.w*f0.w
              + f1.x*f1.x + f1.y*f1.y + f1.z*f1.z + f1.w*f1.w
              + f2.x*f2.x + f2.y*f2.y + f2.z*f2.z + f2.w*f2.w
              + f3.x*f3.x + f3.y*f3.y + f3.z*f3.z + f3.w*f3.w;
      s += __shfl_xor(s, 1, 64);
      s += __shfl_xor(s, 2, 64);
      s += __shfl_xor(s, 4, 64);
      if (c == 0) {
        const float rs = rsqrtf(s);
        sm.nv_l[tt & 1][r] = s * rs;
        sm.rnv_l[r] = rs;
      }
    }
    // ---- pipelined finisher for PREVIOUS tile (overlaps staging VMEM) ----
    if (tt > 0 && t < 64) {
      const int rg = t >> 2, qq = t & 3;
      float sv_n = 0.f, qf = 0.f;
      #pragma unroll
      for (int l = 0; l < 16; ++l) {
        sv_n += sm.red_sv[0][rg][l][qq] + sm.red_sv[1][rg][l][qq];
        qf   += sm.red_qp[0][rg][l][qq] + sm.red_qp[1][rg][l][qq];
      }
      svacc += sv_n / (sm.nv_l[(tt & 1) ^ 1][t] * sqrtf(qf));
      const int hh = t >> 5;
      float ssn = 0.f;
      #pragma unroll
      for (int n2 = 0; n2 < 4; ++n2) ssn += sm.red_s[n2 * 2 + hh][t];
      sm.ssnum[t] += ssn;
    }
    __syncthreads();                   // B2

    // ---- dot MFMA (B-frags from registers) + glue, all in registers ----
    f4v a0 = {0.f,0.f,0.f,0.f}, a1 = {0.f,0.f,0.f,0.f};
    {
      const int ar = nb * 16 + l15;
      #pragma unroll
      for (int ks = 0; ks < 4; ++ks) {
        s8v av = *reinterpret_cast<const s8v*>(&sm.VA[idxV(ar, ks * 32 + g * 8)]);
        a0 = MFMA(av, sfr0[ks], a0);
        a1 = MFMA(av, sfr1[ks], a1);
      }
    }
    float e0[4], e1[4];
    {
      const float4 rv = *reinterpret_cast<const float4*>(&sm.rnv_l[nb * 16 + g * 4]);
      float sv4[4];
      float ss0 = 0.f, ss1 = 0.f;
      unsigned short eb0[4], eb1[4];
      #pragma unroll
      for (int q = 0; q < 4; ++q) {
        const float rvq = (q == 0) ? rv.x : (q == 1) ? rv.y : (q == 2) ? rv.z : rv.w;
        const float c0 = a0[q] * (rvq * rns0r);      // cosine (EPS drop: 1e-16 rel)
        const float c1 = a1[q] * (rvq * rns1r);
        const float e0q = __expf(c0);                // c in [-1,1]: no max-shift needed
        const float e1q = __expf(c1);
        const float w0 = e0q * a0[q], w1 = e1q * a1[q];  // e * rawdot
        sv4[q] = w0 + w1;
        ss0 += w0; ss1 += w1;
        eb0[q] = f2b(e0q); eb1[q] = f2b(e1q);
        const int row = nb * 16 + g * 4 + q;
        sm.Eb[idx64(row, cB0)] = eb0[q];
        sm.Eb[idx64(row, cB1)] = eb1[q];
        e0[q] = e0q; e1[q] = e1q;
      }
      u4v et0 = { eb0[0], eb0[1], eb0[2], eb0[3] };
      u4v et1 = { eb1[0], eb1[1], eb1[2], eb1[3] };
      *reinterpret_cast<u4v*>(&sm.ET[idx64(cB0, nb * 16 + g * 4)]) = et0;
      *reinterpret_cast<u4v*>(&sm.ET[idx64(cB1, nb * 16 + g * 4)]) = et1;
      *reinterpret_cast<float4*>(&sm.red_sv[hf][nb * 4 + g][l15][0]) =
          make_float4(sv4[0], sv4[1], sv4[2], sv4[3]);
      ss0 += __shfl_xor(ss0, 16, 64);  ss0 += __shfl_xor(ss0, 32, 64);
      ss1 += __shfl_xor(ss1, 16, 64);  ss1 += __shfl_xor(ss1, 32, 64);
      if (g == 0) { sm.red_s[w][cB0] = ss0; sm.red_s[w][cB1] = ss1; }
    }
    __syncthreads();                   // B3

    // ---- quad form (E.G, B-frags from registers) ----
    {
      f4v fa0 = {0.f,0.f,0.f,0.f}, fa1 = {0.f,0.f,0.f,0.f};
      #pragma unroll
      for (int ks = 0; ks < 2; ++ks) {
        s8v ea = *reinterpret_cast<const s8v*>(&sm.Eb[idx64(nb * 16 + l15, ks * 32 + g * 8)]);
        fa0 = MFMA(ea, gfr0[ks], fa0);
        fa1 = MFMA(ea, gfr1[ks], fa1);
      }
      *reinterpret_cast<float4*>(&sm.red_qp[hf][nb * 4 + g][l15][0]) =
          make_float4(e0[0]*fa0[0] + e1[0]*fa1[0], e0[1]*fa0[1] + e1[1]*fa1[1],
                      e0[2]*fa0[2] + e1[2]*fa1[2], e0[3]*fa0[3] + e1[3]*fa1[3]);
    }
    // ---- bt += E^T.V via MFMA (B from VT) ----
    {
      const int xr = l15 & 7;
      #pragma unroll
      for (int ks = 0; ks < 2; ++ks) {
        s8v pa = *reinterpret_cast<const s8v*>(&sm.ET[idx64(nb * 16 + l15, ks * 32 + g * 8)]);
        const int k0 = ks * 32 + g * 8;
        #pragma unroll
        for (int dt = 0; dt < 4; ++dt) {
          const int rowv = (hf * 4 + dt) * 16 + l15;
          const int elem = (rowv << 6) + (k0 ^ (((xr ^ (hf * 4 + dt)) & 7) << 3));
          s8v vb = *reinterpret_cast<const s8v*>(&sm.VT[elem]);
          bt4[dt] = MFMA(pa, vb, bt4[dt]);
        }
      }
    }
  }

  // ---- epilogue ----
  __syncthreads();
  if (t < 64) {                        // finisher for tile 7
    const int rg = t >> 2, qq = t & 3;
    float sv_n = 0.f, qf = 0.f;
    #pragma unroll
    for (int l = 0; l < 16; ++l) {
      sv_n += sm.red_sv[0][rg][l][qq] + sm.red_sv[1][rg][l][qq];
      qf   += sm.red_qp[0][rg][l][qq] + sm.red_qp[1][rg][l][qq];
    }
    svacc += sv_n / (sm.nv_l[1][t] * sqrtf(qf));
    const int hh = t >> 5;
    float ssn = 0.f;
    #pragma unroll
    for (int n2 = 0; n2 < 4; ++n2) ssn += sm.red_s[n2 * 2 + hh][t];
    sm.ssnum[t] += ssn;
  }
  __syncthreads();
  {
    float bq[4];
    #pragma unroll
    for (int q = 0; q < 4; ++q)
      bq[q] = bt4[0][q]*bt4[0][q] + bt4[1][q]*bt4[1][q]
            + bt4[2][q]*bt4[2][q] + bt4[3][q]*bt4[3][q];
    *reinterpret_cast<float4*>(&sm.red_qp[hf][nb * 4 + g][l15][0]) =
        make_float4(bq[0], bq[1], bq[2], bq[3]);
  }
  __syncthreads();
  if (t < 64) {
    const int rg = t >> 2, qq = t & 3;
    float btq = 0.f;
    #pragma unroll
    for (int l = 0; l < 16; ++l)
      btq += sm.red_qp[0][rg][l][qq] + sm.red_qp[1][rg][l][qq];
    float ssv = sm.ssnum[t] / (sm.ns_l[t] * sqrtf(btq));
    float svv = svacc;
    #pragma unroll
    for (int msk = 32; msk >= 1; msk >>= 1) {
      ssv += __shfl_xor(ssv, msk, 64);
      svv += __shfl_xor(svv, msk, 64);
    }
    if (t == 0) {
      out[bi * BB + bj]           = svv * (1.0f / NN);
      out[BB * BB + bj * BB + bi] = ssv * (1.0f / MM);  // transposed output
    }
  }
}

extern "C" void kernel_launch(void* const* d_in, const int* in_sizes, int n_in,
                              void* d_out, int out_size, void* d_ws, size_t ws_size,
                              hipStream_t stream) {
  const float* V = (const float*)d_in[0];   // [32, 512, 128] f32
  const float* S = (const float*)d_in[1];   // [32, 64, 128] f32
  float* out = (float*)d_out;               // [2048] f32

  static_assert(sizeof(SMem) <= 80 * 1024, "need 2 blocks/CU");
  hipFuncSetAttribute(reinterpret_cast<const void*>(mv_mfma3),
                      hipFuncAttributeMaxDynamicSharedMemorySize,
                      (int)sizeof(SMem));
  mv_mfma3<<<dim3(BB * BB), dim3(512), sizeof(SMem), stream>>>(V, S, out);
}

// Round 7
// 132.384 us; speedup vs baseline: 1.4628x; 1.1018x over previous
//
#include <hip/hip_runtime.h>
#include <hip/hip_bf16.h>
#include <math.h>

#define BB 32
#define NN 512
#define MM 64
#define DD 128
#define TILE 64
#define NTILES 8

typedef __attribute__((ext_vector_type(8))) short s8v;      // 8 bf16 MFMA A/B frag
typedef __attribute__((ext_vector_type(4))) float f4v;      // MFMA C/D frag
typedef __attribute__((ext_vector_type(4))) unsigned short u4v;
typedef __attribute__((ext_vector_type(8))) unsigned short u8v;

#define MFMA(a, b, c) __builtin_amdgcn_mfma_f32_16x16x32_bf16((a), (b), (c), 0, 0, 0)

__device__ inline unsigned short f2b(float f) {
  union { __hip_bfloat16 b; unsigned short u; } cv;
  cv.b = __float2bfloat16(f);
  return cv.u;
}

// row-swizzles (proven r3-r6): elem ^= (row&7)<<3
__device__ inline int idxV(int r, int k)  { return r * 128 + (k ^ ((r & 7) << 3)); }
__device__ inline int idx64(int r, int k) { return r * 64  + (k ^ ((r & 7) << 3)); }

// ---------------- prep kernel: bf16 pre-swizzled V (VA+VT), S, Gram, norms ----------------
struct __align__(16) PSM {
  unsigned short A[64 * 128];   // VA (V-task) / Sb swizzled (S-task)
  unsigned short B[128 * 64];   // VT (V-task) / Gb swizzled (S-task, 4096 used)
};

extern "C" __global__ void __launch_bounds__(512, 2)
mv_prep(const float* __restrict__ Vg, const float* __restrict__ Sg,
        unsigned short* __restrict__ VAg, unsigned short* __restrict__ VTg,
        unsigned short* __restrict__ Sbg, unsigned short* __restrict__ Gbg,
        float* __restrict__ nvg, float* __restrict__ rnvg,
        float* __restrict__ nsg, float* __restrict__ rnsg)
{
  extern __shared__ char smraw[];
  PSM& sm = *reinterpret_cast<PSM*>(smraw);
  const int t = threadIdx.x;
  const int r = t >> 3, c = t & 7;
  const int bid = blockIdx.x;

  if (bid < 256) {               // ---- V task: i = bid>>3, tile tt = bid&7 ----
    const int i = bid >> 3, tt = bid & 7;
    const float* Vr = Vg + ((size_t)i * NN + tt * TILE + r) * DD + c * 16;
    float4 f0 = reinterpret_cast<const float4*>(Vr)[0];
    float4 f1 = reinterpret_cast<const float4*>(Vr)[1];
    float4 f2 = reinterpret_cast<const float4*>(Vr)[2];
    float4 f3 = reinterpret_cast<const float4*>(Vr)[3];
    unsigned short vb16[16] = {
      f2b(f0.x), f2b(f0.y), f2b(f0.z), f2b(f0.w),
      f2b(f1.x), f2b(f1.y), f2b(f1.z), f2b(f1.w),
      f2b(f2.x), f2b(f2.y), f2b(f2.z), f2b(f2.w),
      f2b(f3.x), f2b(f3.y), f2b(f3.z), f2b(f3.w) };
    u8v lo = { vb16[0], vb16[1], vb16[2], vb16[3], vb16[4], vb16[5], vb16[6], vb16[7] };
    u8v hi = { vb16[8], vb16[9], vb16[10], vb16[11], vb16[12], vb16[13], vb16[14], vb16[15] };
    *reinterpret_cast<u8v*>(&sm.A[idxV(r, c * 16)])     = lo;
    *reinterpret_cast<u8v*>(&sm.A[idxV(r, c * 16 + 8)]) = hi;
    #pragma unroll
    for (int q = 0; q < 8; ++q) {              // VT scatter (write-conflict-engineered, r5)
      const int adr = ((c * 16 + q) << 6) + (r ^ (((q ^ c) & 7) << 3));
      sm.B[adr]       = vb16[q];
      sm.B[adr + 512] = vb16[q + 8];
    }
    float s = f0.x*f0.x + f0.y*f0.y + f0.z*f0.z + f0.w*f0.w
            + f1.x*f1.x + f1.y*f1.y + f1.z*f1.z + f1.w*f1.w
            + f2.x*f2.x + f2.y*f2.y + f2.z*f2.z + f2.w*f2.w
            + f3.x*f3.x + f3.y*f3.y + f3.z*f3.z + f3.w*f3.w;
    s += __shfl_xor(s, 1, 64);
    s += __shfl_xor(s, 2, 64);
    s += __shfl_xor(s, 4, 64);
    if (c == 0) {
      const float rs = rsqrtf(s);
      nvg [i * NN + tt * TILE + r] = s * rs;
      rnvg[i * NN + tt * TILE + r] = rs;
    }
    __syncthreads();
    unsigned short* dA = VAg + (size_t)bid * 8192;
    unsigned short* dB = VTg + (size_t)bid * 8192;
    *reinterpret_cast<u8v*>(&dA[t * 8])        = *reinterpret_cast<u8v*>(&sm.A[t * 8]);
    *reinterpret_cast<u8v*>(&dA[4096 + t * 8]) = *reinterpret_cast<u8v*>(&sm.A[4096 + t * 8]);
    *reinterpret_cast<u8v*>(&dB[t * 8])        = *reinterpret_cast<u8v*>(&sm.B[t * 8]);
    *reinterpret_cast<u8v*>(&dB[4096 + t * 8]) = *reinterpret_cast<u8v*>(&sm.B[4096 + t * 8]);
  } else {                       // ---- S task: j = bid-256 ----
    const int j = bid - 256;
    const float* Sp = Sg + ((size_t)j * MM + r) * DD + c * 16;
    float4 f0 = reinterpret_cast<const float4*>(Sp)[0];
    float4 f1 = reinterpret_cast<const float4*>(Sp)[1];
    float4 f2 = reinterpret_cast<const float4*>(Sp)[2];
    float4 f3 = reinterpret_cast<const float4*>(Sp)[3];
    u8v lo = { f2b(f0.x), f2b(f0.y), f2b(f0.z), f2b(f0.w),
               f2b(f1.x), f2b(f1.y), f2b(f1.z), f2b(f1.w) };
    u8v hi = { f2b(f2.x), f2b(f2.y), f2b(f2.z), f2b(f2.w),
               f2b(f3.x), f2b(f3.y), f2b(f3.z), f2b(f3.w) };
    *reinterpret_cast<u8v*>(&sm.A[idxV(r, c * 16)])     = lo;
    *reinterpret_cast<u8v*>(&sm.A[idxV(r, c * 16 + 8)]) = hi;
    float s = f0.x*f0.x + f0.y*f0.y + f0.z*f0.z + f0.w*f0.w
            + f1.x*f1.x + f1.y*f1.y + f1.z*f1.z + f1.w*f1.w
            + f2.x*f2.x + f2.y*f2.y + f2.z*f2.z + f2.w*f2.w
            + f3.x*f3.x + f3.y*f3.y + f3.z*f3.z + f3.w*f3.w;
    s += __shfl_xor(s, 1, 64);
    s += __shfl_xor(s, 2, 64);
    s += __shfl_xor(s, 4, 64);
    if (c == 0) {
      const float rs = rsqrtf(s);
      nsg [j * MM + r] = s * rs;
      rnsg[j * MM + r] = rs;
    }
    __syncthreads();
    {  // Gram via MFMA (r6 code, reads swizzled sm.A, writes swizzled sm.B)
      const int lane = t & 63, w = t >> 6, l15 = lane & 15, g = lane >> 4;
      const int nb = w >> 1, hf = w & 1, cB0 = hf * 32 + l15, cB1 = cB0 + 16;
      f4v g0 = {0.f,0.f,0.f,0.f}, g1 = {0.f,0.f,0.f,0.f};
      #pragma unroll
      for (int ks = 0; ks < 4; ++ks) {
        s8v a  = *reinterpret_cast<const s8v*>(&sm.A[idxV(nb * 16 + l15, ks * 32 + g * 8)]);
        s8v b0 = *reinterpret_cast<const s8v*>(&sm.A[idxV(cB0,          ks * 32 + g * 8)]);
        s8v b1 = *reinterpret_cast<const s8v*>(&sm.A[idxV(cB1,          ks * 32 + g * 8)]);
        g0 = MFMA(a, b0, g0);
        g1 = MFMA(a, b1, g1);
      }
      #pragma unroll
      for (int q = 0; q < 4; ++q) {
        const int row = nb * 16 + g * 4 + q;
        sm.B[idx64(row, cB0)] = f2b(g0[q]);
        sm.B[idx64(row, cB1)] = f2b(g1[q]);
      }
    }
    __syncthreads();
    // copy out UNswizzled (main reads fragments directly from global)
    unsigned short* dS = Sbg + (size_t)j * 8192;
    *reinterpret_cast<u8v*>(&dS[r * 128 + c * 16])     = *reinterpret_cast<u8v*>(&sm.A[idxV(r, c * 16)]);
    *reinterpret_cast<u8v*>(&dS[r * 128 + c * 16 + 8]) = *reinterpret_cast<u8v*>(&sm.A[idxV(r, c * 16 + 8)]);
    unsigned short* dG = Gbg + (size_t)j * 4096;
    *reinterpret_cast<u8v*>(&dG[r * 64 + c * 8]) = *reinterpret_cast<u8v*>(&sm.B[idx64(r, c * 8)]);
  }
}

// ---------------- main kernel ----------------
struct __align__(16) SMem2 {
  unsigned short VA[8192];      // V bf16 swizzled (dot A)
  unsigned short VT[8192];      // V^T bf16 swizzled (bt B)
  unsigned short Eb[4096];      // E row-major swizzled (quad A)
  unsigned short ET[4096];      // E^T swizzled (bt A)
  float RSV[32 * 68];           // sv partials [hf*16+nb*4+g][l15*4+q]  (2-way max)
  float RQP[32 * 68];           // qf partials; reused for ||bt||^2
  float RS [8 * 68];            // ss col partials [wave][col]
  float nv_lds[512];            // all-tile norms (loaded once)
  float rnv_lds[512];
};

extern "C" __global__ void __launch_bounds__(512, 2)
mv_main(const unsigned short* __restrict__ VAg, const unsigned short* __restrict__ VTg,
        const unsigned short* __restrict__ Sbg, const unsigned short* __restrict__ Gbg,
        const float* __restrict__ nvg, const float* __restrict__ rnvg,
        const float* __restrict__ nsg, const float* __restrict__ rnsg,
        float* __restrict__ out)
{
  extern __shared__ char smraw[];
  SMem2& sm = *reinterpret_cast<SMem2*>(smraw);

  const int t    = threadIdx.x;
  const int lane = t & 63;
  const int w    = t >> 6;
  const int l15  = lane & 15;
  const int g    = lane >> 4;
  const int bi   = blockIdx.x >> 5;
  const int bj   = blockIdx.x & 31;

  const int nb  = w >> 1;
  const int hf  = w & 1;
  const int cB0 = hf * 32 + l15;
  const int cB1 = cB0 + 16;

  // ---- prologue: norms to LDS, frags to regs, tile-0 prefetch ----
  sm.nv_lds[t]  = nvg [bi * NN + t];
  sm.rnv_lds[t] = rnvg[bi * NN + t];

  s8v sfr0[4], sfr1[4], gfr0[2], gfr1[2];
  {
    const unsigned short* Sj = Sbg + (size_t)bj * 8192;
    #pragma unroll
    for (int ks = 0; ks < 4; ++ks) {
      sfr0[ks] = *reinterpret_cast<const s8v*>(&Sj[cB0 * 128 + ks * 32 + g * 8]);
      sfr1[ks] = *reinterpret_cast<const s8v*>(&Sj[cB1 * 128 + ks * 32 + g * 8]);
    }
    const unsigned short* Gj = Gbg + (size_t)bj * 4096;
    #pragma unroll
    for (int ks = 0; ks < 2; ++ks) {
      gfr0[ks] = *reinterpret_cast<const s8v*>(&Gj[cB0 * 64 + ks * 32 + g * 8]);
      gfr1[ks] = *reinterpret_cast<const s8v*>(&Gj[cB1 * 64 + ks * 32 + g * 8]);
    }
  }
  const float rns0r = rnsg[bj * MM + cB0];
  const float rns1r = rnsg[bj * MM + cB1];

  const unsigned short* VAi = VAg + (size_t)(bi * 8) * 8192;
  const unsigned short* VTi = VTg + (size_t)(bi * 8) * 8192;
  u8v p0 = *reinterpret_cast<const u8v*>(&VAi[t * 8]);
  u8v p1 = *reinterpret_cast<const u8v*>(&VAi[4096 + t * 8]);
  u8v p2 = *reinterpret_cast<const u8v*>(&VTi[t * 8]);
  u8v p3 = *reinterpret_cast<const u8v*>(&VTi[4096 + t * 8]);

  f4v bt4[4] = {{0.f,0.f,0.f,0.f},{0.f,0.f,0.f,0.f},{0.f,0.f,0.f,0.f},{0.f,0.f,0.f,0.f}};
  float svacc = 0.f, ssacc = 0.f;

  #pragma unroll 1
  for (int tt = 0; tt < NTILES; ++tt) {
    __syncthreads();                       // B1: prev bt readers of VA/VT/ET done
    // ---- stage from prefetch regs (straight b128 copies; swizzle baked in global) ----
    *reinterpret_cast<u8v*>(&sm.VA[t * 8])        = p0;
    *reinterpret_cast<u8v*>(&sm.VA[4096 + t * 8]) = p1;
    *reinterpret_cast<u8v*>(&sm.VT[t * 8])        = p2;
    *reinterpret_cast<u8v*>(&sm.VT[4096 + t * 8]) = p3;
    if (tt < 7) {                          // issue next-tile loads (latency hides under compute)
      const unsigned short* a = VAi + (size_t)(tt + 1) * 8192;
      const unsigned short* b = VTi + (size_t)(tt + 1) * 8192;
      p0 = *reinterpret_cast<const u8v*>(&a[t * 8]);
      p1 = *reinterpret_cast<const u8v*>(&a[4096 + t * 8]);
      p2 = *reinterpret_cast<const u8v*>(&b[t * 8]);
      p3 = *reinterpret_cast<const u8v*>(&b[4096 + t * 8]);
    }
    // ---- pipelined finisher for previous tile (2-way-conflict layouts) ----
    if (tt > 0 && t < 64) {
      const int rg = t >> 2, qq = t & 3, hh = t >> 5;
      float sv_n = 0.f, qf = 0.f;
      #pragma unroll
      for (int l = 0; l < 16; ++l) {
        sv_n += sm.RSV[rg * 68 + l * 4 + qq] + sm.RSV[(16 + rg) * 68 + l * 4 + qq];
        qf   += sm.RQP[rg * 68 + l * 4 + qq] + sm.RQP[(16 + rg) * 68 + l * 4 + qq];
      }
      svacc += sv_n / (sm.nv_lds[(tt - 1) * TILE + t] * sqrtf(qf));
      float ssn = 0.f;
      #pragma unroll
      for (int n2 = 0; n2 < 4; ++n2) ssn += sm.RS[(n2 * 2 + hh) * 68 + t];
      ssacc += ssn;
    }
    __syncthreads();                       // B2: staging visible

    // ---- dot MFMA (B-frags in regs) + glue ----
    f4v a0 = {0.f,0.f,0.f,0.f}, a1 = {0.f,0.f,0.f,0.f};
    {
      const int ar = nb * 16 + l15;
      #pragma unroll
      for (int ks = 0; ks < 4; ++ks) {
        s8v av = *reinterpret_cast<const s8v*>(&sm.VA[idxV(ar, ks * 32 + g * 8)]);
        a0 = MFMA(av, sfr0[ks], a0);
        a1 = MFMA(av, sfr1[ks], a1);
      }
    }
    float e0[4], e1[4];
    {
      const float4 rv = *reinterpret_cast<const float4*>(&sm.rnv_lds[tt * TILE + nb * 16 + g * 4]);
      float sv4[4];
      float ss0 = 0.f, ss1 = 0.f;
      unsigned short eb0[4], eb1[4];
      #pragma unroll
      for (int q = 0; q < 4; ++q) {
        const float rvq = (q == 0) ? rv.x : (q == 1) ? rv.y : (q == 2) ? rv.z : rv.w;
        const float c0 = a0[q] * (rvq * rns0r);
        const float c1 = a1[q] * (rvq * rns1r);
        const float e0q = __expf(c0);          // c in [-1,1]: no max-shift needed
        const float e1q = __expf(c1);
        const float w0 = e0q * a0[q], w1 = e1q * a1[q];   // e * rawdot
        sv4[q] = w0 + w1;
        ss0 += w0; ss1 += w1;
        eb0[q] = f2b(e0q); eb1[q] = f2b(e1q);
        const int row = nb * 16 + g * 4 + q;
        sm.Eb[idx64(row, cB0)] = eb0[q];
        sm.Eb[idx64(row, cB1)] = eb1[q];
        e0[q] = e0q; e1[q] = e1q;
      }
      u4v et0 = { eb0[0], eb0[1], eb0[2], eb0[3] };
      u4v et1 = { eb1[0], eb1[1], eb1[2], eb1[3] };
      *reinterpret_cast<u4v*>(&sm.ET[idx64(cB0, nb * 16 + g * 4)]) = et0;
      *reinterpret_cast<u4v*>(&sm.ET[idx64(cB1, nb * 16 + g * 4)]) = et1;
      *reinterpret_cast<float4*>(&sm.RSV[(hf * 16 + nb * 4 + g) * 68 + l15 * 4]) =
          make_float4(sv4[0], sv4[1], sv4[2], sv4[3]);
      ss0 += __shfl_xor(ss0, 16, 64);  ss0 += __shfl_xor(ss0, 32, 64);
      ss1 += __shfl_xor(ss1, 16, 64);  ss1 += __shfl_xor(ss1, 32, 64);
      if (g == 0) { sm.RS[w * 68 + cB0] = ss0; sm.RS[w * 68 + cB1] = ss1; }
    }
    __syncthreads();                       // B3: Eb/ET visible

    // ---- quad form (E.G, B-frags in regs) ----
    {
      f4v fa0 = {0.f,0.f,0.f,0.f}, fa1 = {0.f,0.f,0.f,0.f};
      #pragma unroll
      for (int ks = 0; ks < 2; ++ks) {
        s8v ea = *reinterpret_cast<const s8v*>(&sm.Eb[idx64(nb * 16 + l15, ks * 32 + g * 8)]);
        fa0 = MFMA(ea, gfr0[ks], fa0);
        fa1 = MFMA(ea, gfr1[ks], fa1);
      }
      *reinterpret_cast<float4*>(&sm.RQP[(hf * 16 + nb * 4 + g) * 68 + l15 * 4]) =
          make_float4(e0[0]*fa0[0] + e1[0]*fa1[0], e0[1]*fa0[1] + e1[1]*fa1[1],
                      e0[2]*fa0[2] + e1[2]*fa1[2], e0[3]*fa0[3] + e1[3]*fa1[3]);
    }
    // ---- bt += E^T.V via MFMA (B from VT) ----
    {
      const int xr = l15 & 7;
      #pragma unroll
      for (int ks = 0; ks < 2; ++ks) {
        s8v pa = *reinterpret_cast<const s8v*>(&sm.ET[idx64(nb * 16 + l15, ks * 32 + g * 8)]);
        const int k0 = ks * 32 + g * 8;
        #pragma unroll
        for (int dt = 0; dt < 4; ++dt) {
          const int rowv = (hf * 4 + dt) * 16 + l15;
          const int elem = (rowv << 6) + (k0 ^ (((xr ^ (hf * 4 + dt)) & 7) << 3));
          s8v vb = *reinterpret_cast<const s8v*>(&sm.VT[elem]);
          bt4[dt] = MFMA(pa, vb, bt4[dt]);
        }
      }
    }
  }

  // ---- epilogue ----
  __syncthreads();
  if (t < 64) {                            // finisher for tile 7 (before RQP reuse)
    const int rg = t >> 2, qq = t & 3, hh = t >> 5;
    float sv_n = 0.f, qf = 0.f;
    #pragma unroll
    for (int l = 0; l < 16; ++l) {
      sv_n += sm.RSV[rg * 68 + l * 4 + qq] + sm.RSV[(16 + rg) * 68 + l * 4 + qq];
      qf   += sm.RQP[rg * 68 + l * 4 + qq] + sm.RQP[(16 + rg) * 68 + l * 4 + qq];
    }
    svacc += sv_n / (sm.nv_lds[7 * TILE + t] * sqrtf(qf));
    float ssn = 0.f;
    #pragma unroll
    for (int n2 = 0; n2 < 4; ++n2) ssn += sm.RS[(n2 * 2 + hh) * 68 + t];
    ssacc += ssn;
  }
  __syncthreads();
  {
    float bq[4];
    #pragma unroll
    for (int q = 0; q < 4; ++q)
      bq[q] = bt4[0][q]*bt4[0][q] + bt4[1][q]*bt4[1][q]
            + bt4[2][q]*bt4[2][q] + bt4[3][q]*bt4[3][q];
    *reinterpret_cast<float4*>(&sm.RQP[(hf * 16 + nb * 4 + g) * 68 + l15 * 4]) =
        make_float4(bq[0], bq[1], bq[2], bq[3]);
  }
  __syncthreads();
  if (t < 64) {
    const int rg = t >> 2, qq = t & 3;
    float btq = 0.f;
    #pragma unroll
    for (int l = 0; l < 16; ++l)
      btq += sm.RQP[rg * 68 + l * 4 + qq] + sm.RQP[(16 + rg) * 68 + l * 4 + qq];
    float ssv = ssacc / (nsg[bj * MM + t] * sqrtf(btq));
    float svv = svacc;
    #pragma unroll
    for (int msk = 32; msk >= 1; msk >>= 1) {
      ssv += __shfl_xor(ssv, msk, 64);
      svv += __shfl_xor(svv, msk, 64);
    }
    if (t == 0) {
      out[bi * BB + bj]           = svv * (1.0f / NN);
      out[BB * BB + bj * BB + bi] = ssv * (1.0f / MM);  // transposed output
    }
  }
}

extern "C" void kernel_launch(void* const* d_in, const int* in_sizes, int n_in,
                              void* d_out, int out_size, void* d_ws, size_t ws_size,
                              hipStream_t stream) {
  const float* V = (const float*)d_in[0];   // [32, 512, 128] f32
  const float* S = (const float*)d_in[1];   // [32, 64, 128] f32
  float* out = (float*)d_out;               // [2048] f32

  // workspace layout (bytes)
  char* ws = (char*)d_ws;
  unsigned short* VAg = (unsigned short*)(ws + 0);          // 4,194,304
  unsigned short* VTg = (unsigned short*)(ws + 4194304);    // 4,194,304
  unsigned short* Sbg = (unsigned short*)(ws + 8388608);    //   524,288
  unsigned short* Gbg = (unsigned short*)(ws + 8912896);    //   262,144
  float* nvg  = (float*)(ws + 9175040);                     //    65,536
  float* rnvg = (float*)(ws + 9240576);                     //    65,536
  float* nsg  = (float*)(ws + 9306112);                     //     8,192
  float* rnsg = (float*)(ws + 9314304);                     //     8,192  -> total 9,322,496

  static_assert(sizeof(PSM)  <= 160 * 1024, "prep LDS");
  static_assert(sizeof(SMem2) <= 80 * 1024, "main LDS: need 2 blocks/CU");
  hipFuncSetAttribute(reinterpret_cast<const void*>(mv_prep),
                      hipFuncAttributeMaxDynamicSharedMemorySize, (int)sizeof(PSM));
  hipFuncSetAttribute(reinterpret_cast<const void*>(mv_main),
                      hipFuncAttributeMaxDynamicSharedMemorySize, (int)sizeof(SMem2));

  mv_prep<<<dim3(288), dim3(512), sizeof(PSM), stream>>>(
      V, S, VAg, VTg, Sbg, Gbg, nvg, rnvg, nsg, rnsg);
  mv_main<<<dim3(BB * BB), dim3(512), sizeof(SMem2), stream>>>(
      VAg, VTg, Sbg, Gbg, nvg, rnvg, nsg, rnsg, out);
}